// Round 16
// baseline (142.296 us; speedup 1.0000x reference)
//
#include <hip/hip_runtime.h>

typedef _Float16 half8  __attribute__((ext_vector_type(8)));
typedef _Float16 half4  __attribute__((ext_vector_type(4)));
typedef float    floatx4  __attribute__((ext_vector_type(4)));
typedef float    floatx16 __attribute__((ext_vector_type(16)));
typedef unsigned int uint4v __attribute__((ext_vector_type(4)));

constexpr int B_ = 2, S_ = 2048, D_ = 1024, H_ = 16, M_ = 4096;
constexpr int NR_ = B_ * H_ * S_;               // 65536 (b,h,s) rows
constexpr float QSCALE = 0.18033688011112042f;  // log2(e)/8
constexpr int KVB = 64;                         // kv tile
constexpr int HT = 16;                          // tiles per half (1024/64)

__device__ __forceinline__ void gload16(const void* g, void* l) {
  __builtin_amdgcn_global_load_lds((const __attribute__((address_space(1))) void*)g,
                                   (__attribute__((address_space(3))) void*)l, 16, 0, 0);
}

// ---------------------------------------------------------------------------
// cast fp32 -> fp16, 8 elems/thread
// ---------------------------------------------------------------------------
__global__ __launch_bounds__(256) void cast_f32_f16(const float* __restrict__ in,
                                                    _Float16* __restrict__ out, int n8) {
  int i = blockIdx.x * 256 + threadIdx.x;
  if (i >= n8) return;
  float4 a = reinterpret_cast<const float4*>(in)[2 * i];
  float4 b = reinterpret_cast<const float4*>(in)[2 * i + 1];
  half8 h;
  h[0] = (_Float16)a.x; h[1] = (_Float16)a.y; h[2] = (_Float16)a.z; h[3] = (_Float16)a.w;
  h[4] = (_Float16)b.x; h[5] = (_Float16)b.y; h[6] = (_Float16)b.z; h[7] = (_Float16)b.w;
  reinterpret_cast<half8*>(out)[i] = h;
}

// ---------------------------------------------------------------------------
// W[K][N] fp32 -> WT[N][K] fp16 (64x64 tiles). z selects {W_qkv, W_out}.
// ---------------------------------------------------------------------------
__global__ __launch_bounds__(256) void transpose_cast2(const float* __restrict__ W0,
                                                       _Float16* __restrict__ WT0,
                                                       const float* __restrict__ W1,
                                                       _Float16* __restrict__ WT1) {
  __shared__ float Ws[64][65];
  const int z = blockIdx.z;
  const int NW = z ? D_ : 3 * D_;
  if (blockIdx.x * 64 >= NW) return;
  const float* W = z ? W1 : W0;
  _Float16* WT = z ? WT1 : WT0;
  const int K = D_, N = NW;
  const int n0 = blockIdx.x * 64, k0 = blockIdx.y * 64;
  const int t = threadIdx.x;
#pragma unroll
  for (int i = 0; i < 4; i++) {
    int idx = t + 256 * i;
    int r = idx >> 4, c4 = idx & 15;
    float4 v = *reinterpret_cast<const float4*>(W + (size_t)(k0 + r) * N + n0 + c4 * 4);
    Ws[r][c4 * 4 + 0] = v.x; Ws[r][c4 * 4 + 1] = v.y;
    Ws[r][c4 * 4 + 2] = v.z; Ws[r][c4 * 4 + 3] = v.w;
  }
  __syncthreads();
#pragma unroll
  for (int i = 0; i < 2; i++) {
    int idx = t + 256 * i;
    int r = idx >> 3, ck = idx & 7;
    half8 h;
#pragma unroll
    for (int j = 0; j < 8; j++) h[j] = (_Float16)Ws[ck * 8 + j][r];
    *reinterpret_cast<half8*>(WT + (size_t)(n0 + r) * K + k0 + ck * 8) = h;
  }
}

// ---------------------------------------------------------------------------
// 256x192 fp16 MFMA GEMM (R14 wave-tiling), fine-interleaved staging,
// fused V-transpose epilogue (R15).
// ---------------------------------------------------------------------------
__global__ __launch_bounds__(512, 2) void gemm256_mfma(
    const _Float16* __restrict__ A, const _Float16* __restrict__ BT,
    const float* __restrict__ bias, _Float16* __restrict__ Cout,
    _Float16* __restrict__ Vt,
    int M, int N, int K, float scale_lo, int ncut) {
  extern __shared__ char smem[];   // 114688 B: As[2][32K] | Bs[2][24K]
  const int tid = threadIdx.x, w = tid >> 6, lane = tid & 63;
  const int wm = w >> 1, wn = w & 1;   // 4 waves down M, 2 across N

  const int nwg = gridDim.x, cpx = nwg >> 3;
  const int wg = (blockIdx.x & 7) * cpx + (blockIdx.x >> 3);
  const int nbx = N / 192;
  const int bx = wg % nbx, by = wg / nbx;
  const int m0 = by * 256, n0 = bx * 192;

  const int NT = K >> 6;

  const int rS = tid >> 3, cS = (tid & 7) ^ (rS & 7);
  const char* Apn = (const char*)(A + (size_t)(m0 + rS) * K + cS * 8);
  const char* Bpn = (const char*)(BT + (size_t)(n0 + rS) * K + cS * 8);
  const size_t strideI = (size_t)64 * K * 2;   // 64 rows per load-slice

  auto stageA1 = [&](int buf, int i) {
    gload16(Apn + i * strideI, smem + buf * 32768 + tid * 16 + i * 8192);
  };
  auto stageB1 = [&](int buf, int i) {
    gload16(Bpn + i * strideI, smem + 65536 + buf * 24576 + tid * 16 + i * 8192);
  };

  floatx4 acc[4][6] = {};

#pragma unroll
  for (int i = 0; i < 4; i++) stageA1(0, i);
#pragma unroll
  for (int i = 0; i < 3; i++) stageB1(0, i);
  Apn += 128; Bpn += 128;

  for (int kt = 0; kt < NT; ++kt) {
    const int p = kt & 1;
    asm volatile("s_waitcnt vmcnt(0)" ::: "memory");
    __builtin_amdgcn_s_barrier();
    __builtin_amdgcn_sched_barrier(0);   // no ds_read hoist above the barrier

    const char* Ab = smem + p * 32768;
    const char* Bb = smem + 65536 + p * 24576;
    const bool more = (kt + 1 < NT);

    half8 bf[6][2];
#pragma unroll
    for (int n = 0; n < 6; n++)
#pragma unroll
      for (int ks = 0; ks < 2; ks++) {
        int row = wn * 96 + n * 16 + (lane & 15);
        int ch = (ks * 4 + (lane >> 4)) ^ (row & 7);
        bf[n][ks] = *reinterpret_cast<const half8*>(Bb + row * 128 + ch * 16);
      }

#pragma unroll
    for (int q = 0; q < 4; q++) {
      half8 af[2];
#pragma unroll
      for (int ks = 0; ks < 2; ks++) {
        int row = wm * 64 + q * 16 + (lane & 15);
        int ch = (ks * 4 + (lane >> 4)) ^ (row & 7);
        af[ks] = *reinterpret_cast<const half8*>(Ab + row * 128 + ch * 16);
      }
      if (more) {
        if (q == 0)      { stageA1(p ^ 1, 0); stageA1(p ^ 1, 1); }
        else if (q == 1) { stageA1(p ^ 1, 2); stageA1(p ^ 1, 3); }
        else if (q == 2) { stageB1(p ^ 1, 0); stageB1(p ^ 1, 1); }
        else             { stageB1(p ^ 1, 2); }
      }
      __builtin_amdgcn_s_setprio(1);
#pragma unroll
      for (int ks = 0; ks < 2; ks++)
#pragma unroll
        for (int n = 0; n < 6; n++)
          acc[q][n] = __builtin_amdgcn_mfma_f32_16x16x32_f16(
              af[ks], bf[n][ks], acc[q][n], 0, 0, 0);
      __builtin_amdgcn_s_setprio(0);
    }
    Apn += 128; Bpn += 128;
    __builtin_amdgcn_sched_barrier(0);   // no ds_read sink below the barrier
    __builtin_amdgcn_s_barrier();
  }

#pragma unroll
  for (int mf = 0; mf < 4; mf++)
#pragma unroll
    for (int n = 0; n < 6; n++) {
      int col = n0 + wn * 96 + n * 16 + (lane & 15);
      float bv = bias[col];
      float sc = (col < ncut) ? scale_lo : 1.0f;
      int row0 = m0 + wm * 64 + mf * 16 + (lane >> 4) * 4;
      half4 hv;
#pragma unroll
      for (int reg = 0; reg < 4; reg++) {
        float v = (acc[mf][n][reg] + bv) * sc;
        _Float16 hvv = (_Float16)v;
        Cout[(size_t)(row0 + reg) * N + col] = hvv;
        hv[reg] = hvv;
      }
      if (col >= 2 * D_) {   // fused V-transpose
        int d = col - 2 * D_;
        int bb = row0 >> 11, s0 = row0 & 2047;
        _Float16* vt = Vt + ((size_t)(bb * H_ + (d >> 6)) * 64 + (d & 63)) * S_ + s0;
        *reinterpret_cast<half4*>(vt) = hv;
      }
    }
}

// ---------------------------------------------------------------------------
// 128x128 fp16 MFMA GEMM (output projection), fp32 out.
// R16: FUSED COMBINE — A is reg-staged from the two KV-split partials:
// k-tile kt == head h, so A-tile(kt) = a0*Opart[0][gr][:] + a1*Opart[1][gr][:]
// with gr = (b*16+kt)*2048 + s and softmax weights from keys. Blend lands in
// the SAME linear LDS slot the old global_load_lds wrote (pre-swizzled global
// source chunk cS + linear dest) -> fragment reads unchanged. lgkmcnt(0)
// before the trailing barrier guarantees ds_writes land before consumers
// (rule 18/21). B staging unchanged (global_load_lds + vmcnt(0) at tile top).
// Replaces the flash_combine kernel (-16 MB read, -8 MB write, -1 launch).
// ---------------------------------------------------------------------------
__global__ __launch_bounds__(256, 2) void gemm128_mfma(
    const _Float16* __restrict__ Opart, const float* __restrict__ keys,
    const _Float16* __restrict__ BT,
    const float* __restrict__ bias, float* __restrict__ Cout,
    int M, int N, int K) {
  extern __shared__ char smem[];   // 65536 B: As[2][16K] | Bs[2][16K]
  const int tid = threadIdx.x, w = tid >> 6, lane = tid & 63;
  const int wm = w >> 1, wn = w & 1;

  const int nwg = gridDim.x, cpx = nwg >> 3;
  const int wg = (blockIdx.x & 7) * cpx + (blockIdx.x >> 3);
  const int nbx = N >> 7;
  const int bx = wg % nbx, by = wg / nbx;
  const int m0 = by * 128, n0 = bx * 128;

  const int NT = K >> 6;

  const int rS = tid >> 3, cS = (tid & 7) ^ (rS & 7);
  const char* Bpn = (const char*)(BT + (size_t)(n0 + rS) * K + cS * 8);
  const size_t strideI = (size_t)32 * K * 2;   // 32 rows per load-slice

  // A-rows handled by this thread: rA(i) = m0 + rS + 32*i; b and s components
  const int rAb = (m0 + rS) >> 11;             // batch (tile never crosses b)
  const int rAs = (m0 + rS) & 2047;            // s base (+32*i per slice)

  auto stageA1 = [&](int buf, int kt, int i) {   // fused combine, reg-staged
    int gr = (rAb * 16 + kt) * 2048 + rAs + 32 * i;
    float k0 = keys[gr], k1 = keys[NR_ + gr];
    float mx = fmaxf(k0, k1);
    float w0 = __builtin_amdgcn_exp2f(k0 - mx);
    float w1 = __builtin_amdgcn_exp2f(k1 - mx);
    float inv = 1.0f / (w0 + w1);
    float a0 = w0 * inv, a1 = w1 * inv;
    half8 x0 = *reinterpret_cast<const half8*>(Opart + (size_t)gr * 64 + cS * 8);
    half8 x1 = *reinterpret_cast<const half8*>(Opart + ((size_t)NR_ + gr) * 64 + cS * 8);
    half8 o;
#pragma unroll
    for (int j = 0; j < 8; j++)
      o[j] = (_Float16)(a0 * (float)x0[j] + a1 * (float)x1[j]);
    *reinterpret_cast<half8*>(smem + buf * 16384 + tid * 16 + i * 4096) = o;
  };
  auto stageB1 = [&](int buf, int i) {
    gload16(Bpn + i * strideI, smem + 32768 + buf * 16384 + tid * 16 + i * 4096);
  };

  floatx4 acc[4][4] = {};

#pragma unroll
  for (int i = 0; i < 4; i++) stageA1(0, 0, i);
#pragma unroll
  for (int i = 0; i < 4; i++) stageB1(0, i);
  Bpn += 128;
  asm volatile("s_waitcnt lgkmcnt(0)" ::: "memory");  // prologue A writes landed

  for (int kt = 0; kt < NT; ++kt) {
    const int p = kt & 1;
    asm volatile("s_waitcnt vmcnt(0)" ::: "memory");  // B tile landed
    __builtin_amdgcn_s_barrier();
    __builtin_amdgcn_sched_barrier(0);   // no ds_read hoist above the barrier

    const char* Ab = smem + p * 16384;
    const char* Bb = smem + 32768 + p * 16384;
    const bool more = (kt + 1 < NT);

    half8 bf[4][2];
#pragma unroll
    for (int n = 0; n < 4; n++)
#pragma unroll
      for (int ks = 0; ks < 2; ks++) {
        int row = wn * 64 + n * 16 + (lane & 15);
        int ch = (ks * 4 + (lane >> 4)) ^ (row & 7);
        bf[n][ks] = *reinterpret_cast<const half8*>(Bb + row * 128 + ch * 16);
      }

#pragma unroll
    for (int q = 0; q < 4; q++) {
      half8 af[2];
#pragma unroll
      for (int ks = 0; ks < 2; ks++) {
        int row = wm * 64 + q * 16 + (lane & 15);
        int ch = (ks * 4 + (lane >> 4)) ^ (row & 7);
        af[ks] = *reinterpret_cast<const half8*>(Ab + row * 128 + ch * 16);
      }
      if (more) {
        if (q == 0)      { stageA1(p ^ 1, kt + 1, 0); stageA1(p ^ 1, kt + 1, 1); }
        else if (q == 1) { stageA1(p ^ 1, kt + 1, 2); stageA1(p ^ 1, kt + 1, 3); }
        else if (q == 2) { stageB1(p ^ 1, 0); stageB1(p ^ 1, 1); }
        else             { stageB1(p ^ 1, 2); stageB1(p ^ 1, 3); }
      }
      __builtin_amdgcn_s_setprio(1);
#pragma unroll
      for (int ks = 0; ks < 2; ks++)
#pragma unroll
        for (int n = 0; n < 4; n++)
          acc[q][n] = __builtin_amdgcn_mfma_f32_16x16x32_f16(
              af[ks], bf[n][ks], acc[q][n], 0, 0, 0);
      __builtin_amdgcn_s_setprio(0);
    }
    Bpn += 128;
    asm volatile("s_waitcnt lgkmcnt(0)" ::: "memory");  // A ds_writes landed
    __builtin_amdgcn_sched_barrier(0);   // no ds op sink below the barrier
    __builtin_amdgcn_s_barrier();
  }

#pragma unroll
  for (int q = 0; q < 4; q++)
#pragma unroll
    for (int n = 0; n < 4; n++) {
      int col = n0 + wn * 64 + n * 16 + (lane & 15);
      float bv = bias[col];
#pragma unroll
      for (int reg = 0; reg < 4; reg++) {
        int row = m0 + wm * 64 + q * 16 + (lane >> 4) * 4 + reg;
        Cout[(size_t)row * N + col] = acc[q][n][reg] + bv;
      }
    }
}

// ---------------------------------------------------------------------------
// Flash attention — R13 structure (near trans-bound floor for D=64).
// ---------------------------------------------------------------------------
__global__ __launch_bounds__(256, 4) void flash_mfma(const _Float16* __restrict__ qkv,
                                                     const _Float16* __restrict__ Vt,
                                                     _Float16* __restrict__ Opart,
                                                     float* __restrict__ keys) {
  const int qt = blockIdx.x, h = blockIdx.y;
  const int b = blockIdx.z >> 1, sp = blockIdx.z & 1;
  const int t = threadIdx.x, w = t >> 6, lane = t & 63;
  const int lo = lane & 31, hi = lane >> 5;

  __shared__ _Float16 Ks[2][KVB * 64];    // [kk][d] rows 128B, chunk^(r&7)
  __shared__ _Float16 Vts[2][64 * KVB];   // [d][kk] rows 128B, chunk^(r&7)

  const int qrow = qt * 128 + w * 32 + lo;
  const _Float16* qbase = qkv + (size_t)(b * S_ + qrow) * (3 * D_) + h * 64;
  half8 qf[4];
#pragma unroll
  for (int kd = 0; kd < 4; kd++)
    qf[kd] = *reinterpret_cast<const half8*>(qbase + kd * 16 + hi * 8);
  asm volatile("" : "+v"(qf[0]), "+v"(qf[1]), "+v"(qf[2]), "+v"(qf[3]));

  const size_t kbase = (size_t)(b * S_) * (3 * D_) + D_ + h * 64;
  const size_t vbase = (size_t)(b * H_ + h) * 64 * S_;
  const int kvbase = sp * (S_ / 2);

  const int rs = t >> 3, cs = (t & 7) ^ (rs & 7);
  const char* kp = (const char*)(qkv + kbase + (size_t)(kvbase + rs) * (3 * D_) + cs * 8);
  const char* vp = (const char*)(Vt + vbase + (size_t)rs * S_ + kvbase + cs * 8);
  constexpr size_t K_ROW32 = (size_t)32 * 3 * D_ * 2;
  constexpr size_t V_ROW32 = (size_t)32 * S_ * 2;
  constexpr size_t K_TILE  = (size_t)KVB * 3 * D_ * 2;
  constexpr size_t V_TILE  = (size_t)KVB * 2;

  auto stage = [&](int buf) {
    char* kd_ = (char*)&Ks[buf][0] + t * 16;
    char* vd_ = (char*)&Vts[buf][0] + t * 16;
    gload16(kp, kd_);
    gload16(kp + K_ROW32, kd_ + 4096);
    gload16(vp, vd_);
    gload16(vp + V_ROW32, vd_ + 4096);
  };

  floatx16 o0, o1;
#pragma unroll
  for (int r = 0; r < 16; r++) { o0[r] = 0.f; o1[r] = 0.f; }
  float m = -1e30f, l = 0.f;

  stage(0);
  kp += K_TILE; vp += V_TILE;

#pragma unroll 2
  for (int tt = 0; tt < HT; ++tt) {
    const int cb = tt & 1;
    if (tt + 1 < HT) {
      stage(cb ^ 1);
      kp += K_TILE; vp += V_TILE;
      asm volatile("s_waitcnt vmcnt(4)" ::: "memory");
    } else {
      asm volatile("s_waitcnt vmcnt(0)" ::: "memory");
    }
    __builtin_amdgcn_s_barrier();
    __builtin_amdgcn_sched_barrier(0);   // no ds_read hoist above the barrier

    const char* kb2 = (const char*)&Ks[cb][0];
    floatx16 s0v, s1v;
#pragma unroll
    for (int r = 0; r < 16; r++) { s0v[r] = 0.f; s1v[r] = 0.f; }
    __builtin_amdgcn_s_setprio(1);
#pragma unroll
    for (int kd = 0; kd < 4; kd++) {
      int r0 = lo, r1 = 32 + lo;
      half8 k0f = *reinterpret_cast<const half8*>(
          kb2 + r0 * 128 + (((kd * 2 + hi) ^ (r0 & 7)) * 16));
      half8 k1f = *reinterpret_cast<const half8*>(
          kb2 + r1 * 128 + (((kd * 2 + hi) ^ (r1 & 7)) * 16));
      s0v = __builtin_amdgcn_mfma_f32_32x32x16_f16(k0f, qf[kd], s0v, 0, 0, 0);
      s1v = __builtin_amdgcn_mfma_f32_32x32x16_f16(k1f, qf[kd], s1v, 0, 0, 0);
    }
    __builtin_amdgcn_s_setprio(0);

    float tm[16];
#pragma unroll
    for (int r = 0; r < 16; r++) tm[r] = fmaxf(s0v[r], s1v[r]);
    float u0 = fmaxf(fmaxf(tm[0], tm[1]), tm[2]);
    float u1 = fmaxf(fmaxf(tm[3], tm[4]), tm[5]);
    float u2 = fmaxf(fmaxf(tm[6], tm[7]), tm[8]);
    float u3 = fmaxf(fmaxf(tm[9], tm[10]), tm[11]);
    float u4 = fmaxf(fmaxf(tm[12], tm[13]), tm[14]);
    float pm = fmaxf(fmaxf(u0, u1), u2);
    pm = fmaxf(fmaxf(pm, u3), u4);
    pm = fmaxf(pm, tm[15]);
    pm = fmaxf(pm, __shfl_xor(pm, 32));
    if (!__all(pm <= m + 8.0f)) {
      float mn = fmaxf(m, pm);
      float al = __builtin_amdgcn_exp2f(m - mn);
      m = mn; l *= al;
#pragma unroll
      for (int r = 0; r < 16; r++) { o0[r] *= al; o1[r] *= al; }
    }
    float rr[16];
#pragma unroll
    for (int r = 0; r < 16; r++) {
      s0v[r] = __builtin_amdgcn_exp2f(s0v[r] - m);
      s1v[r] = __builtin_amdgcn_exp2f(s1v[r] - m);
      rr[r] = s0v[r] + s1v[r];
    }
#pragma unroll
    for (int st = 8; st >= 1; st >>= 1)
#pragma unroll
      for (int r = 0; r < st; r++) rr[r] += rr[r + st];
    float rs2 = rr[0];
    rs2 += __shfl_xor(rs2, 32);
    l += rs2;

    half8 pf0a, pf0b, pf1a, pf1b;
    {
      unsigned a0 = __builtin_bit_cast(unsigned, __builtin_amdgcn_cvt_pkrtz(s0v[0], s0v[1]));
      unsigned b0 = __builtin_bit_cast(unsigned, __builtin_amdgcn_cvt_pkrtz(s0v[4], s0v[5]));
      unsigned a1 = __builtin_bit_cast(unsigned, __builtin_amdgcn_cvt_pkrtz(s0v[2], s0v[3]));
      unsigned b1 = __builtin_bit_cast(unsigned, __builtin_amdgcn_cvt_pkrtz(s0v[6], s0v[7]));
      asm("v_permlane32_swap_b32 %0, %1" : "+v"(a0), "+v"(b0));
      asm("v_permlane32_swap_b32 %0, %1" : "+v"(a1), "+v"(b1));
      uint4v u; u[0] = a0; u[1] = a1; u[2] = b0; u[3] = b1;
      pf0a = __builtin_bit_cast(half8, u);
      a0 = __builtin_bit_cast(unsigned, __builtin_amdgcn_cvt_pkrtz(s0v[8], s0v[9]));
      b0 = __builtin_bit_cast(unsigned, __builtin_amdgcn_cvt_pkrtz(s0v[12], s0v[13]));
      a1 = __builtin_bit_cast(unsigned, __builtin_amdgcn_cvt_pkrtz(s0v[10], s0v[11]));
      b1 = __builtin_bit_cast(unsigned, __builtin_amdgcn_cvt_pkrtz(s0v[14], s0v[15]));
      asm("v_permlane32_swap_b32 %0, %1" : "+v"(a0), "+v"(b0));
      asm("v_permlane32_swap_b32 %0, %1" : "+v"(a1), "+v"(b1));
      u[0] = a0; u[1] = a1; u[2] = b0; u[3] = b1;
      pf0b = __builtin_bit_cast(half8, u);
      a0 = __builtin_bit_cast(unsigned, __builtin_amdgcn_cvt_pkrtz(s1v[0], s1v[1]));
      b0 = __builtin_bit_cast(unsigned, __builtin_amdgcn_cvt_pkrtz(s1v[4], s1v[5]));
      a1 = __builtin_bit_cast(unsigned, __builtin_amdgcn_cvt_pkrtz(s1v[2], s1v[3]));
      b1 = __builtin_bit_cast(unsigned, __builtin_amdgcn_cvt_pkrtz(s1v[6], s1v[7]));
      asm("v_permlane32_swap_b32 %0, %1" : "+v"(a0), "+v"(b0));
      asm("v_permlane32_swap_b32 %0, %1" : "+v"(a1), "+v"(b1));
      u[0] = a0; u[1] = a1; u[2] = b0; u[3] = b1;
      pf1a = __builtin_bit_cast(half8, u);
      a0 = __builtin_bit_cast(unsigned, __builtin_amdgcn_cvt_pkrtz(s1v[8], s1v[9]));
      b0 = __builtin_bit_cast(unsigned, __builtin_amdgcn_cvt_pkrtz(s1v[12], s1v[13]));
      a1 = __builtin_bit_cast(unsigned, __builtin_amdgcn_cvt_pkrtz(s1v[10], s1v[11]));
      b1 = __builtin_bit_cast(unsigned, __builtin_amdgcn_cvt_pkrtz(s1v[14], s1v[15]));
      asm("v_permlane32_swap_b32 %0, %1" : "+v"(a0), "+v"(b0));
      asm("v_permlane32_swap_b32 %0, %1" : "+v"(a1), "+v"(b1));
      u[0] = a0; u[1] = a1; u[2] = b0; u[3] = b1;
      pf1b = __builtin_bit_cast(half8, u);
    }

    const char* vb2 = (const char*)&Vts[cb][0];
    __builtin_amdgcn_s_setprio(1);
#pragma unroll
    for (int ks = 0; ks < 4; ks++) {
      half8 pf = (ks == 0) ? pf0a : (ks == 1) ? pf0b : (ks == 2) ? pf1a : pf1b;
      const int ch = ks * 2 + hi;
      half8 vf0 = *reinterpret_cast<const half8*>(vb2 + lo * 128 + ((ch ^ (lo & 7)) * 16));
      half8 vf1 = *reinterpret_cast<const half8*>(vb2 + (lo + 32) * 128 + ((ch ^ (lo & 7)) * 16));
      o0 = __builtin_amdgcn_mfma_f32_32x32x16_f16(vf0, pf, o0, 0, 0, 0);
      o1 = __builtin_amdgcn_mfma_f32_32x32x16_f16(vf1, pf, o1, 0, 0, 0);
    }
    __builtin_amdgcn_s_setprio(0);

    __builtin_amdgcn_sched_barrier(0);   // no ds_read sink below the barrier
    __builtin_amdgcn_s_barrier();
  }

  float inv = 1.0f / l;
  const int gr = (b * H_ + h) * S_ + qrow;
  _Float16* ob = Opart + ((size_t)sp * NR_ + gr) * 64;
#pragma unroll
  for (int mt = 0; mt < 2; mt++)
#pragma unroll
    for (int rq = 0; rq < 4; rq++) {
      half4 v;
#pragma unroll
      for (int e = 0; e < 4; e++) v[e] = (_Float16)(((mt ? o1 : o0)[4 * rq + e]) * inv);
      *reinterpret_cast<half4*>(ob + 32 * mt + 8 * rq + 4 * hi) = v;
    }
  if (hi == 0) keys[sp * NR_ + gr] = m + __log2f(l);
}

// ---------------------------------------------------------------------------
extern "C" void kernel_launch(void* const* d_in, const int* in_sizes, int n_in,
                              void* d_out, int out_size, void* d_ws, size_t ws_size,
                              hipStream_t stream) {
  const float* x     = (const float*)d_in[0];
  const float* W_qkv = (const float*)d_in[1];
  const float* b_qkv = (const float*)d_in[2];
  const float* W_out = (const float*)d_in[3];
  const float* b_out = (const float*)d_in[4];
  float* out = (float*)d_out;

  _Float16* xh    = (_Float16*)d_ws;
  _Float16* qkvh  = xh + (size_t)M_ * D_;
  _Float16* Vth   = qkvh + (size_t)M_ * 3 * D_;
  _Float16* WoT   = Vth + (size_t)B_ * H_ * 64 * S_;
  _Float16* WqT   = WoT + (size_t)D_ * D_;
  _Float16* Opart = WqT;                                  // alias (WqT dead by flash)
  float*    keys  = (float*)(Opart + (size_t)2 * NR_ * 64);

  cast_f32_f16<<<(M_ * D_ / 8 + 255) / 256, 256, 0, stream>>>(x, xh, M_ * D_ / 8);
  transpose_cast2<<<dim3(3 * D_ / 64, D_ / 64, 2), 256, 0, stream>>>(
      W_qkv, WqT, W_out, WoT);

  gemm256_mfma<<<256, 512, 114688, stream>>>(
      xh, WqT, b_qkv, qkvh, Vth, M_, 3 * D_, D_, QSCALE, D_);

  flash_mfma<<<dim3(S_ / 128, H_, B_ * 2), 256, 0, stream>>>(qkvh, Vth, Opart, keys);

  // output projection with fused KV-split combine (flash_combine eliminated)
  gemm128_mfma<<<256, 256, 65536, stream>>>(
      Opart, keys, WoT, b_out, out, M_, D_, D_);
}

// Round 17
// 121.654 us; speedup vs baseline: 1.1697x; 1.1697x over previous
//
#include <hip/hip_runtime.h>

typedef _Float16 half8  __attribute__((ext_vector_type(8)));
typedef _Float16 half4  __attribute__((ext_vector_type(4)));
typedef float    floatx4  __attribute__((ext_vector_type(4)));
typedef float    floatx16 __attribute__((ext_vector_type(16)));
typedef unsigned int uint4v __attribute__((ext_vector_type(4)));

constexpr int B_ = 2, S_ = 2048, D_ = 1024, H_ = 16, M_ = 4096;
constexpr int NR_ = B_ * H_ * S_;               // 65536 (b,h,s) rows
constexpr float QSCALE = 0.18033688011112042f;  // log2(e)/8
constexpr int KVB = 64;                         // kv tile
constexpr int HT = 16;                          // tiles per half (1024/64)

__device__ __forceinline__ void gload16(const void* g, void* l) {
  __builtin_amdgcn_global_load_lds((const __attribute__((address_space(1))) void*)g,
                                   (__attribute__((address_space(3))) void*)l, 16, 0, 0);
}

// ---------------------------------------------------------------------------
// Merged prepass (R17): one launch for x-cast + both weight transposes.
// blocks [0,2048): cast x (fp32->fp16, 8/thread)
// blocks [2048,2816): W_qkv transpose-cast 64x64 tiles (48x16)
// blocks [2816,3072): W_out transpose-cast 64x64 tiles (16x16)
// ---------------------------------------------------------------------------
__global__ __launch_bounds__(256) void prepass(const float* __restrict__ x,
                                               _Float16* __restrict__ xh,
                                               const float* __restrict__ W0,
                                               _Float16* __restrict__ WT0,
                                               const float* __restrict__ W1,
                                               _Float16* __restrict__ WT1) {
  __shared__ float Ws[64][65];
  int bid = blockIdx.x;
  const int t = threadIdx.x;
  if (bid < 2048) {
    int i = bid * 256 + t;                      // < M*D/8 = 524288 always
    float4 a = reinterpret_cast<const float4*>(x)[2 * i];
    float4 b = reinterpret_cast<const float4*>(x)[2 * i + 1];
    half8 h;
    h[0] = (_Float16)a.x; h[1] = (_Float16)a.y; h[2] = (_Float16)a.z; h[3] = (_Float16)a.w;
    h[4] = (_Float16)b.x; h[5] = (_Float16)b.y; h[6] = (_Float16)b.z; h[7] = (_Float16)b.w;
    reinterpret_cast<half8*>(xh)[i] = h;
    return;
  }
  bid -= 2048;
  const float* W; _Float16* WT; int N;
  if (bid < 768) { W = W0; WT = WT0; N = 3 * D_; }
  else           { bid -= 768; W = W1; WT = WT1; N = D_; }
  const int K = D_;
  const int nbx = N >> 6;
  const int n0 = (bid % nbx) * 64, k0 = (bid / nbx) * 64;
#pragma unroll
  for (int i = 0; i < 4; i++) {
    int idx = t + 256 * i;
    int r = idx >> 4, c4 = idx & 15;
    float4 v = *reinterpret_cast<const float4*>(W + (size_t)(k0 + r) * N + n0 + c4 * 4);
    Ws[r][c4 * 4 + 0] = v.x; Ws[r][c4 * 4 + 1] = v.y;
    Ws[r][c4 * 4 + 2] = v.z; Ws[r][c4 * 4 + 3] = v.w;
  }
  __syncthreads();
#pragma unroll
  for (int i = 0; i < 2; i++) {
    int idx = t + 256 * i;
    int r = idx >> 3, ck = idx & 7;
    half8 h;
#pragma unroll
    for (int j = 0; j < 8; j++) h[j] = (_Float16)Ws[ck * 8 + j][r];
    *reinterpret_cast<half8*>(WT + (size_t)(n0 + r) * K + k0 + ck * 8) = h;
  }
}

// ---------------------------------------------------------------------------
// 256x192 fp16 MFMA GEMM (R14 wave-tiling), fine-interleaved staging,
// fused V-transpose epilogue (R15). Race-proven skeleton.
// ---------------------------------------------------------------------------
__global__ __launch_bounds__(512, 2) void gemm256_mfma(
    const _Float16* __restrict__ A, const _Float16* __restrict__ BT,
    const float* __restrict__ bias, _Float16* __restrict__ Cout,
    _Float16* __restrict__ Vt,
    int M, int N, int K, float scale_lo, int ncut) {
  extern __shared__ char smem[];   // 114688 B: As[2][32K] | Bs[2][24K]
  const int tid = threadIdx.x, w = tid >> 6, lane = tid & 63;
  const int wm = w >> 1, wn = w & 1;   // 4 waves down M, 2 across N

  const int nwg = gridDim.x, cpx = nwg >> 3;
  const int wg = (blockIdx.x & 7) * cpx + (blockIdx.x >> 3);
  const int nbx = N / 192;
  const int bx = wg % nbx, by = wg / nbx;
  const int m0 = by * 256, n0 = bx * 192;

  const int NT = K >> 6;

  const int rS = tid >> 3, cS = (tid & 7) ^ (rS & 7);
  const char* Apn = (const char*)(A + (size_t)(m0 + rS) * K + cS * 8);
  const char* Bpn = (const char*)(BT + (size_t)(n0 + rS) * K + cS * 8);
  const size_t strideI = (size_t)64 * K * 2;   // 64 rows per load-slice

  auto stageA1 = [&](int buf, int i) {
    gload16(Apn + i * strideI, smem + buf * 32768 + tid * 16 + i * 8192);
  };
  auto stageB1 = [&](int buf, int i) {
    gload16(Bpn + i * strideI, smem + 65536 + buf * 24576 + tid * 16 + i * 8192);
  };

  floatx4 acc[4][6] = {};

#pragma unroll
  for (int i = 0; i < 4; i++) stageA1(0, i);
#pragma unroll
  for (int i = 0; i < 3; i++) stageB1(0, i);
  Apn += 128; Bpn += 128;

  for (int kt = 0; kt < NT; ++kt) {
    const int p = kt & 1;
    asm volatile("s_waitcnt vmcnt(0)" ::: "memory");
    __builtin_amdgcn_s_barrier();
    __builtin_amdgcn_sched_barrier(0);   // no ds_read hoist above the barrier

    const char* Ab = smem + p * 32768;
    const char* Bb = smem + 65536 + p * 24576;
    const bool more = (kt + 1 < NT);

    half8 bf[6][2];
#pragma unroll
    for (int n = 0; n < 6; n++)
#pragma unroll
      for (int ks = 0; ks < 2; ks++) {
        int row = wn * 96 + n * 16 + (lane & 15);
        int ch = (ks * 4 + (lane >> 4)) ^ (row & 7);
        bf[n][ks] = *reinterpret_cast<const half8*>(Bb + row * 128 + ch * 16);
      }

#pragma unroll
    for (int q = 0; q < 4; q++) {
      half8 af[2];
#pragma unroll
      for (int ks = 0; ks < 2; ks++) {
        int row = wm * 64 + q * 16 + (lane & 15);
        int ch = (ks * 4 + (lane >> 4)) ^ (row & 7);
        af[ks] = *reinterpret_cast<const half8*>(Ab + row * 128 + ch * 16);
      }
      if (more) {
        if (q == 0)      { stageA1(p ^ 1, 0); stageA1(p ^ 1, 1); }
        else if (q == 1) { stageA1(p ^ 1, 2); stageA1(p ^ 1, 3); }
        else if (q == 2) { stageB1(p ^ 1, 0); stageB1(p ^ 1, 1); }
        else             { stageB1(p ^ 1, 2); }
      }
      __builtin_amdgcn_s_setprio(1);
#pragma unroll
      for (int ks = 0; ks < 2; ks++)
#pragma unroll
        for (int n = 0; n < 6; n++)
          acc[q][n] = __builtin_amdgcn_mfma_f32_16x16x32_f16(
              af[ks], bf[n][ks], acc[q][n], 0, 0, 0);
      __builtin_amdgcn_s_setprio(0);
    }
    Apn += 128; Bpn += 128;
    __builtin_amdgcn_sched_barrier(0);   // no ds_read sink below the barrier
    __builtin_amdgcn_s_barrier();
  }

#pragma unroll
  for (int mf = 0; mf < 4; mf++)
#pragma unroll
    for (int n = 0; n < 6; n++) {
      int col = n0 + wn * 96 + n * 16 + (lane & 15);
      float bv = bias[col];
      float sc = (col < ncut) ? scale_lo : 1.0f;
      int row0 = m0 + wm * 64 + mf * 16 + (lane >> 4) * 4;
      half4 hv;
#pragma unroll
      for (int reg = 0; reg < 4; reg++) {
        float v = (acc[mf][n][reg] + bv) * sc;
        _Float16 hvv = (_Float16)v;
        Cout[(size_t)(row0 + reg) * N + col] = hvv;
        hv[reg] = hvv;
      }
      if (col >= 2 * D_) {   // fused V-transpose
        int d = col - 2 * D_;
        int bb = row0 >> 11, s0 = row0 & 2047;
        _Float16* vt = Vt + ((size_t)(bb * H_ + (d >> 6)) * 64 + (d & 63)) * S_ + s0;
        *reinterpret_cast<half4*>(vt) = hv;
      }
    }
}

// ---------------------------------------------------------------------------
// 128x128 fp16 MFMA GEMM (output projection), fine-interleaved, fp32 out.
// (R13 version — R16's fused combine REVERTED: reg-staged A put a dependent
// load->blend->ds_write chain + lgkm drains on the critical path, +17 us.)
// ---------------------------------------------------------------------------
__global__ __launch_bounds__(256, 2) void gemm128_mfma(
    const _Float16* __restrict__ A, const _Float16* __restrict__ BT,
    const float* __restrict__ bias, float* __restrict__ Cout,
    int M, int N, int K) {
  extern __shared__ char smem[];   // 65536 B: As[2][16K] | Bs[2][16K]
  const int tid = threadIdx.x, w = tid >> 6, lane = tid & 63;
  const int wm = w >> 1, wn = w & 1;

  const int nwg = gridDim.x, cpx = nwg >> 3;
  const int wg = (blockIdx.x & 7) * cpx + (blockIdx.x >> 3);
  const int nbx = N >> 7;
  const int bx = wg % nbx, by = wg / nbx;
  const int m0 = by * 128, n0 = bx * 128;

  const int NT = K >> 6;

  const int rS = tid >> 3, cS = (tid & 7) ^ (rS & 7);
  const char* Apn = (const char*)(A + (size_t)(m0 + rS) * K + cS * 8);
  const char* Bpn = (const char*)(BT + (size_t)(n0 + rS) * K + cS * 8);
  const size_t strideI = (size_t)32 * K * 2;   // 32 rows per load-slice

  auto stageA1 = [&](int buf, int i) {
    gload16(Apn + i * strideI, smem + buf * 16384 + tid * 16 + i * 4096);
  };
  auto stageB1 = [&](int buf, int i) {
    gload16(Bpn + i * strideI, smem + 32768 + buf * 16384 + tid * 16 + i * 4096);
  };

  floatx4 acc[4][4] = {};

#pragma unroll
  for (int i = 0; i < 4; i++) stageA1(0, i);
#pragma unroll
  for (int i = 0; i < 4; i++) stageB1(0, i);
  Apn += 128; Bpn += 128;

  for (int kt = 0; kt < NT; ++kt) {
    const int p = kt & 1;
    asm volatile("s_waitcnt vmcnt(0)" ::: "memory");
    __builtin_amdgcn_s_barrier();
    __builtin_amdgcn_sched_barrier(0);

    const char* Ab = smem + p * 16384;
    const char* Bb = smem + 32768 + p * 16384;
    const bool more = (kt + 1 < NT);

    half8 bf[4][2];
#pragma unroll
    for (int n = 0; n < 4; n++)
#pragma unroll
      for (int ks = 0; ks < 2; ks++) {
        int row = wn * 64 + n * 16 + (lane & 15);
        int ch = (ks * 4 + (lane >> 4)) ^ (row & 7);
        bf[n][ks] = *reinterpret_cast<const half8*>(Bb + row * 128 + ch * 16);
      }

#pragma unroll
    for (int q = 0; q < 4; q++) {
      half8 af[2];
#pragma unroll
      for (int ks = 0; ks < 2; ks++) {
        int row = wm * 64 + q * 16 + (lane & 15);
        int ch = (ks * 4 + (lane >> 4)) ^ (row & 7);
        af[ks] = *reinterpret_cast<const half8*>(Ab + row * 128 + ch * 16);
      }
      if (more) {
        if (q == 0)      { stageA1(p ^ 1, 0); stageA1(p ^ 1, 1); }
        else if (q == 1) { stageA1(p ^ 1, 2); stageA1(p ^ 1, 3); }
        else if (q == 2) { stageB1(p ^ 1, 0); stageB1(p ^ 1, 1); }
        else             { stageB1(p ^ 1, 2); stageB1(p ^ 1, 3); }
      }
      __builtin_amdgcn_s_setprio(1);
#pragma unroll
      for (int ks = 0; ks < 2; ks++)
#pragma unroll
        for (int n = 0; n < 4; n++)
          acc[q][n] = __builtin_amdgcn_mfma_f32_16x16x32_f16(
              af[ks], bf[n][ks], acc[q][n], 0, 0, 0);
      __builtin_amdgcn_s_setprio(0);
    }
    Apn += 128; Bpn += 128;
    __builtin_amdgcn_sched_barrier(0);
    __builtin_amdgcn_s_barrier();
  }

#pragma unroll
  for (int q = 0; q < 4; q++)
#pragma unroll
    for (int n = 0; n < 4; n++) {
      int col = n0 + wn * 64 + n * 16 + (lane & 15);
      float bv = bias[col];
#pragma unroll
      for (int reg = 0; reg < 4; reg++) {
        int row = m0 + wm * 64 + q * 16 + (lane >> 4) * 4 + reg;
        Cout[(size_t)row * N + col] = acc[q][n][reg] + bv;
      }
    }
}

// ---------------------------------------------------------------------------
// Flash attention — R13 structure (near trans-bound floor for D=64).
// ---------------------------------------------------------------------------
__global__ __launch_bounds__(256, 4) void flash_mfma(const _Float16* __restrict__ qkv,
                                                     const _Float16* __restrict__ Vt,
                                                     _Float16* __restrict__ Opart,
                                                     float* __restrict__ keys) {
  const int qt = blockIdx.x, h = blockIdx.y;
  const int b = blockIdx.z >> 1, sp = blockIdx.z & 1;
  const int t = threadIdx.x, w = t >> 6, lane = t & 63;
  const int lo = lane & 31, hi = lane >> 5;

  __shared__ _Float16 Ks[2][KVB * 64];    // [kk][d] rows 128B, chunk^(r&7)
  __shared__ _Float16 Vts[2][64 * KVB];   // [d][kk] rows 128B, chunk^(r&7)

  const int qrow = qt * 128 + w * 32 + lo;
  const _Float16* qbase = qkv + (size_t)(b * S_ + qrow) * (3 * D_) + h * 64;
  half8 qf[4];
#pragma unroll
  for (int kd = 0; kd < 4; kd++)
    qf[kd] = *reinterpret_cast<const half8*>(qbase + kd * 16 + hi * 8);
  asm volatile("" : "+v"(qf[0]), "+v"(qf[1]), "+v"(qf[2]), "+v"(qf[3]));

  const size_t kbase = (size_t)(b * S_) * (3 * D_) + D_ + h * 64;
  const size_t vbase = (size_t)(b * H_ + h) * 64 * S_;
  const int kvbase = sp * (S_ / 2);

  const int rs = t >> 3, cs = (t & 7) ^ (rs & 7);
  const char* kp = (const char*)(qkv + kbase + (size_t)(kvbase + rs) * (3 * D_) + cs * 8);
  const char* vp = (const char*)(Vt + vbase + (size_t)rs * S_ + kvbase + cs * 8);
  constexpr size_t K_ROW32 = (size_t)32 * 3 * D_ * 2;
  constexpr size_t V_ROW32 = (size_t)32 * S_ * 2;
  constexpr size_t K_TILE  = (size_t)KVB * 3 * D_ * 2;
  constexpr size_t V_TILE  = (size_t)KVB * 2;

  auto stage = [&](int buf) {
    char* kd_ = (char*)&Ks[buf][0] + t * 16;
    char* vd_ = (char*)&Vts[buf][0] + t * 16;
    gload16(kp, kd_);
    gload16(kp + K_ROW32, kd_ + 4096);
    gload16(vp, vd_);
    gload16(vp + V_ROW32, vd_ + 4096);
  };

  floatx16 o0, o1;
#pragma unroll
  for (int r = 0; r < 16; r++) { o0[r] = 0.f; o1[r] = 0.f; }
  float m = -1e30f, l = 0.f;

  stage(0);
  kp += K_TILE; vp += V_TILE;

#pragma unroll 2
  for (int tt = 0; tt < HT; ++tt) {
    const int cb = tt & 1;
    if (tt + 1 < HT) {
      stage(cb ^ 1);
      kp += K_TILE; vp += V_TILE;
      asm volatile("s_waitcnt vmcnt(4)" ::: "memory");
    } else {
      asm volatile("s_waitcnt vmcnt(0)" ::: "memory");
    }
    __builtin_amdgcn_s_barrier();
    __builtin_amdgcn_sched_barrier(0);   // no ds_read hoist above the barrier

    const char* kb2 = (const char*)&Ks[cb][0];
    floatx16 s0v, s1v;
#pragma unroll
    for (int r = 0; r < 16; r++) { s0v[r] = 0.f; s1v[r] = 0.f; }
    __builtin_amdgcn_s_setprio(1);
#pragma unroll
    for (int kd = 0; kd < 4; kd++) {
      int r0 = lo, r1 = 32 + lo;
      half8 k0f = *reinterpret_cast<const half8*>(
          kb2 + r0 * 128 + (((kd * 2 + hi) ^ (r0 & 7)) * 16));
      half8 k1f = *reinterpret_cast<const half8*>(
          kb2 + r1 * 128 + (((kd * 2 + hi) ^ (r1 & 7)) * 16));
      s0v = __builtin_amdgcn_mfma_f32_32x32x16_f16(k0f, qf[kd], s0v, 0, 0, 0);
      s1v = __builtin_amdgcn_mfma_f32_32x32x16_f16(k1f, qf[kd], s1v, 0, 0, 0);
    }
    __builtin_amdgcn_s_setprio(0);

    float tm[16];
#pragma unroll
    for (int r = 0; r < 16; r++) tm[r] = fmaxf(s0v[r], s1v[r]);
    float u0 = fmaxf(fmaxf(tm[0], tm[1]), tm[2]);
    float u1 = fmaxf(fmaxf(tm[3], tm[4]), tm[5]);
    float u2 = fmaxf(fmaxf(tm[6], tm[7]), tm[8]);
    float u3 = fmaxf(fmaxf(tm[9], tm[10]), tm[11]);
    float u4 = fmaxf(fmaxf(tm[12], tm[13]), tm[14]);
    float pm = fmaxf(fmaxf(u0, u1), u2);
    pm = fmaxf(fmaxf(pm, u3), u4);
    pm = fmaxf(pm, tm[15]);
    pm = fmaxf(pm, __shfl_xor(pm, 32));
    if (!__all(pm <= m + 8.0f)) {
      float mn = fmaxf(m, pm);
      float al = __builtin_amdgcn_exp2f(m - mn);
      m = mn; l *= al;
#pragma unroll
      for (int r = 0; r < 16; r++) { o0[r] *= al; o1[r] *= al; }
    }
    float rr[16];
#pragma unroll
    for (int r = 0; r < 16; r++) {
      s0v[r] = __builtin_amdgcn_exp2f(s0v[r] - m);
      s1v[r] = __builtin_amdgcn_exp2f(s1v[r] - m);
      rr[r] = s0v[r] + s1v[r];
    }
#pragma unroll
    for (int st = 8; st >= 1; st >>= 1)
#pragma unroll
      for (int r = 0; r < st; r++) rr[r] += rr[r + st];
    float rs2 = rr[0];
    rs2 += __shfl_xor(rs2, 32);
    l += rs2;

    half8 pf0a, pf0b, pf1a, pf1b;
    {
      unsigned a0 = __builtin_bit_cast(unsigned, __builtin_amdgcn_cvt_pkrtz(s0v[0], s0v[1]));
      unsigned b0 = __builtin_bit_cast(unsigned, __builtin_amdgcn_cvt_pkrtz(s0v[4], s0v[5]));
      unsigned a1 = __builtin_bit_cast(unsigned, __builtin_amdgcn_cvt_pkrtz(s0v[2], s0v[3]));
      unsigned b1 = __builtin_bit_cast(unsigned, __builtin_amdgcn_cvt_pkrtz(s0v[6], s0v[7]));
      asm("v_permlane32_swap_b32 %0, %1" : "+v"(a0), "+v"(b0));
      asm("v_permlane32_swap_b32 %0, %1" : "+v"(a1), "+v"(b1));
      uint4v u; u[0] = a0; u[1] = a1; u[2] = b0; u[3] = b1;
      pf0a = __builtin_bit_cast(half8, u);
      a0 = __builtin_bit_cast(unsigned, __builtin_amdgcn_cvt_pkrtz(s0v[8], s0v[9]));
      b0 = __builtin_bit_cast(unsigned, __builtin_amdgcn_cvt_pkrtz(s0v[12], s0v[13]));
      a1 = __builtin_bit_cast(unsigned, __builtin_amdgcn_cvt_pkrtz(s0v[10], s0v[11]));
      b1 = __builtin_bit_cast(unsigned, __builtin_amdgcn_cvt_pkrtz(s0v[14], s0v[15]));
      asm("v_permlane32_swap_b32 %0, %1" : "+v"(a0), "+v"(b0));
      asm("v_permlane32_swap_b32 %0, %1" : "+v"(a1), "+v"(b1));
      u[0] = a0; u[1] = a1; u[2] = b0; u[3] = b1;
      pf0b = __builtin_bit_cast(half8, u);
      a0 = __builtin_bit_cast(unsigned, __builtin_amdgcn_cvt_pkrtz(s1v[0], s1v[1]));
      b0 = __builtin_bit_cast(unsigned, __builtin_amdgcn_cvt_pkrtz(s1v[4], s1v[5]));
      a1 = __builtin_bit_cast(unsigned, __builtin_amdgcn_cvt_pkrtz(s1v[2], s1v[3]));
      b1 = __builtin_bit_cast(unsigned, __builtin_amdgcn_cvt_pkrtz(s1v[6], s1v[7]));
      asm("v_permlane32_swap_b32 %0, %1" : "+v"(a0), "+v"(b0));
      asm("v_permlane32_swap_b32 %0, %1" : "+v"(a1), "+v"(b1));
      u[0] = a0; u[1] = a1; u[2] = b0; u[3] = b1;
      pf1a = __builtin_bit_cast(half8, u);
      a0 = __builtin_bit_cast(unsigned, __builtin_amdgcn_cvt_pkrtz(s1v[8], s1v[9]));
      b0 = __builtin_bit_cast(unsigned, __builtin_amdgcn_cvt_pkrtz(s1v[12], s1v[13]));
      a1 = __builtin_bit_cast(unsigned, __builtin_amdgcn_cvt_pkrtz(s1v[10], s1v[11]));
      b1 = __builtin_bit_cast(unsigned, __builtin_amdgcn_cvt_pkrtz(s1v[14], s1v[15]));
      asm("v_permlane32_swap_b32 %0, %1" : "+v"(a0), "+v"(b0));
      asm("v_permlane32_swap_b32 %0, %1" : "+v"(a1), "+v"(b1));
      u[0] = a0; u[1] = a1; u[2] = b0; u[3] = b1;
      pf1b = __builtin_bit_cast(half8, u);
    }

    const char* vb2 = (const char*)&Vts[cb][0];
    __builtin_amdgcn_s_setprio(1);
#pragma unroll
    for (int ks = 0; ks < 4; ks++) {
      half8 pf = (ks == 0) ? pf0a : (ks == 1) ? pf0b : (ks == 2) ? pf1a : pf1b;
      const int ch = ks * 2 + hi;
      half8 vf0 = *reinterpret_cast<const half8*>(vb2 + lo * 128 + ((ch ^ (lo & 7)) * 16));
      half8 vf1 = *reinterpret_cast<const half8*>(vb2 + (lo + 32) * 128 + ((ch ^ (lo & 7)) * 16));
      o0 = __builtin_amdgcn_mfma_f32_32x32x16_f16(vf0, pf, o0, 0, 0, 0);
      o1 = __builtin_amdgcn_mfma_f32_32x32x16_f16(vf1, pf, o1, 0, 0, 0);
    }
    __builtin_amdgcn_s_setprio(0);

    __builtin_amdgcn_sched_barrier(0);   // no ds_read sink below the barrier
    __builtin_amdgcn_s_barrier();
  }

  float inv = 1.0f / l;
  const int gr = (b * H_ + h) * S_ + qrow;
  _Float16* ob = Opart + ((size_t)sp * NR_ + gr) * 64;
#pragma unroll
  for (int mt = 0; mt < 2; mt++)
#pragma unroll
    for (int rq = 0; rq < 4; rq++) {
      half4 v;
#pragma unroll
      for (int e = 0; e < 4; e++) v[e] = (_Float16)(((mt ? o1 : o0)[4 * rq + e]) * inv);
      *reinterpret_cast<half4*>(ob + 32 * mt + 8 * rq + 4 * hi) = v;
    }
  if (hi == 0) keys[sp * NR_ + gr] = m + __log2f(l);
}

// ---------------------------------------------------------------------------
// Combine the two KV-split halves: out = (w0*O0 + w1*O1)/(w0+w1), wi = 2^keyi
// ---------------------------------------------------------------------------
__global__ __launch_bounds__(256) void flash_combine(const _Float16* __restrict__ Opart,
                                                     const float* __restrict__ keys,
                                                     _Float16* __restrict__ attn_out) {
  const int gr = blockIdx.x * 256 + threadIdx.x;
  const float k0 = keys[gr], k1 = keys[NR_ + gr];
  const float mx = fmaxf(k0, k1);
  const float w0 = __builtin_amdgcn_exp2f(k0 - mx);
  const float w1 = __builtin_amdgcn_exp2f(k1 - mx);
  const float inv = 1.0f / (w0 + w1);
  const float a0 = w0 * inv, a1 = w1 * inv;
  const int bh = gr >> 11, qs = gr & 2047, b = bh >> 4, h = bh & 15;
  const half8* p0 = reinterpret_cast<const half8*>(Opart + (size_t)gr * 64);
  const half8* p1 = reinterpret_cast<const half8*>(Opart + ((size_t)NR_ + gr) * 64);
  half8* ob = reinterpret_cast<half8*>(
      attn_out + ((size_t)(b * S_ + qs)) * D_ + h * 64);
#pragma unroll
  for (int j = 0; j < 8; j++) {
    half8 x0 = p0[j], x1 = p1[j];
    half8 o;
#pragma unroll
    for (int e = 0; e < 8; e++)
      o[e] = (_Float16)(a0 * (float)x0[e] + a1 * (float)x1[e]);
    ob[j] = o;
  }
}

// ---------------------------------------------------------------------------
extern "C" void kernel_launch(void* const* d_in, const int* in_sizes, int n_in,
                              void* d_out, int out_size, void* d_ws, size_t ws_size,
                              hipStream_t stream) {
  const float* x     = (const float*)d_in[0];
  const float* W_qkv = (const float*)d_in[1];
  const float* b_qkv = (const float*)d_in[2];
  const float* W_out = (const float*)d_in[3];
  const float* b_out = (const float*)d_in[4];
  float* out = (float*)d_out;

  _Float16* xh    = (_Float16*)d_ws;
  _Float16* qkvh  = xh + (size_t)M_ * D_;
  _Float16* Vth   = qkvh + (size_t)M_ * 3 * D_;
  _Float16* WoT   = Vth + (size_t)B_ * H_ * 64 * S_;
  _Float16* WqT   = WoT + (size_t)D_ * D_;
  _Float16* Opart = WqT;                                  // alias (WqT dead by flash)
  float*    keys  = (float*)(Opart + (size_t)2 * NR_ * 64);
  _Float16* atth  = xh;                                   // alias (xh dead by combine)

  // merged prepass: x-cast + both weight transposes in one launch
  prepass<<<3072, 256, 0, stream>>>(x, xh, W_qkv, WqT, W_out, WoT);

  gemm256_mfma<<<256, 512, 114688, stream>>>(
      xh, WqT, b_qkv, qkvh, Vth, M_, 3 * D_, D_, QSCALE, D_);

  flash_mfma<<<dim3(S_ / 128, H_, B_ * 2), 256, 0, stream>>>(qkvh, Vth, Opart, keys);

  flash_combine<<<NR_ / 256, 256, 0, stream>>>(Opart, keys, atth);

  gemm128_mfma<<<256, 256, 65536, stream>>>(
      atth, WoT, b_out, out, M_, D_, D_);
}